// Round 6
// baseline (383.730 us; speedup 1.0000x reference)
//
#include <hip/hip_runtime.h>
#include <hip/hip_fp16.h>

#define N 8192
#define D 128

typedef _Float16 f16x8 __attribute__((ext_vector_type(8)));
typedef float    f32x4 __attribute__((ext_vector_type(4)));

// ws layout: [0,2MB) Yh fp16[8192][128]; [4MB, 4MB+24KB) partials[6144]
//   partials[0..4095]    = per-tile-block masked loss (x0.5 applied)
//   partials[4096..6143] = per-prep-block reg term (x lmbd/2 applied)
#define YH_OFF    0
#define PART_OFF  (4u * 1024 * 1024)
#define NPART     (4096 + 2048)

__device__ __forceinline__ float wave_reduce(float p) {
    #pragma unroll
    for (int off = 32; off > 0; off >>= 1)
        p += __shfl_xor(p, off, 64);
    return p;
}

// K0: Yh = fp16(W + b), plus the regularizer partials. 4 rows per block.
__global__ __launch_bounds__(256)
void gf_prep_kernel(const float* __restrict__ W, const float* __restrict__ b,
                    __half* __restrict__ Yh, float* __restrict__ partials) {
    __shared__ float s_bsum[4];
    const int lane = threadIdx.x & 63;
    const int w    = threadIdx.x >> 6;
    const int row  = blockIdx.x * 4 + w;

    const float2 bb = ((const float2*)b)[lane];
    float2 y = ((const float2*)(W + (size_t)row * D))[lane];
    y.x += bb.x; y.y += bb.y;
    __half2 h;
    h.x = __float2half_rn(y.x);
    h.y = __float2half_rn(y.y);
    ((__half2*)(Yh + (size_t)row * D))[lane] = h;

    const float reg = wave_reduce(y.x * y.x + y.y * y.y);
    if (lane == 0) s_bsum[w] = reg;
    __syncthreads();
    if (threadIdx.x == 0)
        partials[4096 + blockIdx.x] = 0.05f * (s_bsum[0] + s_bsum[1] + s_bsum[2] + s_bsum[3]);
}

// K1: SDDMM as dense tiled GEMM. Block = 128x128 C-tile, 4 waves = 2x2
// quadrants of 64x64. Each wave: acc[4][4] 16x16 MFMA tiles, K=128 in 4 steps
// of 32. Y-frags load straight from global (Yh is 2 MB -> L2/L3-hot).
// Epilogue: stream the 64x64 A sub-tile (the only HBM-bound traffic, read
// exactly once across the whole grid) and accumulate masked (a - p)^2.
// A-frag layout: row = lane&15, k = (lane>>4)*8 + e (contiguous 16B/lane).
// C/D layout:    col = lane&15, row = (lane>>4)*4 + reg   [m89-verified].
__global__ __launch_bounds__(256)
void gf_tile_kernel(const float* __restrict__ A,
                    const __half* __restrict__ Yh,
                    float* __restrict__ partials) {
    __shared__ float s_bsum[4];
    const int lane = threadIdx.x & 63;
    const int w    = threadIdx.x >> 6;
    const int tx   = blockIdx.x & 63;          // j-tile index
    const int ty   = blockIdx.x >> 6;          // i-tile index
    const int i0   = ty * 128 + (w >> 1) * 64; // this wave's quadrant
    const int j0   = tx * 128 + (w & 1) * 64;
    const int lr   = lane & 15;                // row/col within 16-tile
    const int kg   = lane >> 4;                // k-group / C-row-group

    f32x4 acc[4][4];
    #pragma unroll
    for (int bi = 0; bi < 4; ++bi)
        #pragma unroll
        for (int bj = 0; bj < 4; ++bj)
            acc[bi][bj] = (f32x4){0.f, 0.f, 0.f, 0.f};

    // ---- K-loop: 4 steps of k=32 ----
    #pragma unroll
    for (int ks = 0; ks < 4; ++ks) {
        f16x8 af[4], bf[4];
        #pragma unroll
        for (int t = 0; t < 4; ++t) {
            af[t] = *(const f16x8*)(Yh + (size_t)(i0 + t * 16 + lr) * D + ks * 32 + kg * 8);
            bf[t] = *(const f16x8*)(Yh + (size_t)(j0 + t * 16 + lr) * D + ks * 32 + kg * 8);
        }
        #pragma unroll
        for (int bi = 0; bi < 4; ++bi)
            #pragma unroll
            for (int bj = 0; bj < 4; ++bj)
                acc[bi][bj] = __builtin_amdgcn_mfma_f32_16x16x32_f16(
                    af[bi], bf[bj], acc[bi][bj], 0, 0, 0);
    }

    // ---- Epilogue: masked loss over this wave's 64x64 A sub-tile ----
    // Per (bi): batch 16 scalar loads (4 rows x 4 bj) -> 4 consecutive 64B
    // segments per instr, bj-adjacent addresses merge into full lines in L2.
    float loss = 0.0f;
    #pragma unroll
    for (int bi = 0; bi < 4; ++bi) {
        float a[4][4];
        #pragma unroll
        for (int r = 0; r < 4; ++r) {
            const float* Ap = A + (size_t)(i0 + bi * 16 + kg * 4 + r) * N + j0 + lr;
            #pragma unroll
            for (int bj = 0; bj < 4; ++bj)
                a[r][bj] = Ap[bj * 16];
        }
        #pragma unroll
        for (int r = 0; r < 4; ++r)
            #pragma unroll
            for (int bj = 0; bj < 4; ++bj) {
                const float av = a[r][bj];
                if (av > 0.0f) {
                    const float d = av - acc[bi][bj][r];
                    loss += d * d;
                }
            }
    }

    loss = wave_reduce(loss);
    if (lane == 0) s_bsum[w] = loss;
    __syncthreads();
    if (threadIdx.x == 0)
        partials[blockIdx.x] = 0.5f * (s_bsum[0] + s_bsum[1] + s_bsum[2] + s_bsum[3]);
}

// Sum NPART partials -> out[0].
__global__ __launch_bounds__(256)
void gf_reduce_kernel(const float* __restrict__ partials, float* __restrict__ out) {
    __shared__ float s_ws[4];
    const int lane = threadIdx.x & 63;
    const int w    = threadIdx.x >> 6;
    float s = 0.0f;
    for (int i = threadIdx.x; i < NPART; i += 256) s += partials[i];
    s = wave_reduce(s);
    if (lane == 0) s_ws[w] = s;
    __syncthreads();
    if (threadIdx.x == 0) out[0] = s_ws[0] + s_ws[1] + s_ws[2] + s_ws[3];
}

extern "C" void kernel_launch(void* const* d_in, const int* in_sizes, int n_in,
                              void* d_out, int out_size, void* d_ws, size_t ws_size,
                              hipStream_t stream) {
    const float* A = (const float*)d_in[0];
    const float* W = (const float*)d_in[1];
    const float* b = (const float*)d_in[2];
    float* out = (float*)d_out;

    char*   ws       = (char*)d_ws;
    __half* Yh       = (__half*)(ws + YH_OFF);
    float*  partials = (float*)(ws + PART_OFF);

    gf_prep_kernel<<<dim3(N / 4), dim3(256), 0, stream>>>(W, b, Yh, partials);
    gf_tile_kernel<<<dim3(4096), dim3(256), 0, stream>>>(A, Yh, partials);
    gf_reduce_kernel<<<dim3(1), dim3(256), 0, stream>>>(partials, out);
}